// Round 2
// baseline (27000.977 us; speedup 1.0000x reference)
//
#include <hip/hip_runtime.h>
#include <hip/hip_bf16.h>

#define SS 512
#define II 1024
#define HH 1024
#define NELEM (32 * SS * II)   // B*S*I elements of x

typedef short bf16x8 __attribute__((ext_vector_type(8)));
typedef float f32x4 __attribute__((ext_vector_type(4)));

__device__ __forceinline__ short f2bf_s(float f) {
    union { float fv; unsigned int i; } v; v.fv = f;
    unsigned int r = v.i + 0x7FFF + ((v.i >> 16) & 1);  // RNE
    return (short)(r >> 16);
}
__device__ __forceinline__ float sigm(float x)   { return 1.0f / (1.0f + __expf(-x)); }
__device__ __forceinline__ float tanh_f(float x) { return 2.0f / (1.0f + __expf(-2.0f * x)) - 1.0f; }

__device__ __forceinline__ bf16x8 cvt8(const float* p) {
    bf16x8 r;
#pragma unroll
    for (int j = 0; j < 8; ++j) r[j] = f2bf_s(p[j]);
    return r;
}

// Device-wide barrier: 8 padded sub-counters per slot, 32 blocks each.
// Every wave acquire-polls so each consumer wave's later plain loads see
// invalidated L1/L2.
__device__ __forceinline__ void grid_barrier(unsigned int* cnt, int tid, int l, int sub) {
    __threadfence();                // all threads fence their own stores
    __syncthreads();
    if (tid == 0)
        __hip_atomic_fetch_add(cnt + sub * 16, 1u,
                               __ATOMIC_RELEASE, __HIP_MEMORY_SCOPE_AGENT);
    if (l < 8) {
        while (__hip_atomic_load(cnt + l * 16,
                                 __ATOMIC_ACQUIRE, __HIP_MEMORY_SCOPE_AGENT) < 32u)
            __builtin_amdgcn_s_sleep(1);
    }
    __syncthreads();
}

// Persistent BiLSTM. Grid 256x256. Block g: direction d=g>>7, owns 8 h-units.
// f32 inputs; weights converted to bf16 fragments once, register-resident for
// all 512 steps. 4 waves K-split -> partial C[32b x 32col] -> LDS reduce ->
// gates + c/h update (f32 state). h exchanged via bf16 ping-pong in ws with a
// per-step device-scope barrier.
template <int USE_XB>
__global__ void __launch_bounds__(256, 1)
bilstm_persist(const float* __restrict__ x,
               const float* __restrict__ Wii_f, const float* __restrict__ Whi_f,
               const float* __restrict__ bi_f,
               const float* __restrict__ Wii_r, const float* __restrict__ Whi_r,
               const float* __restrict__ bi_r,
               float* __restrict__ out, ushort* hb, unsigned int* flags,
               ushort* xb)
{
    const int g   = blockIdx.x;
    const int d   = g >> 7;
    const int u0  = (g & 127) * 8;
    const int tid = threadIdx.x;
    const int w   = tid >> 6;
    const int l   = tid & 63;
    const int q   = l >> 4;
    const int ln  = l & 15;
    const int kw  = w * 256;
    const int sub = g & 7;

    // ---- phase 0 (optional): cooperative x f32 -> bf16 into ws ----
    if (USE_XB) {
        const int gtid = g * 256 + tid;
        for (int base = gtid * 8; base < NELEM; base += 256 * 256 * 8) {
            *(bf16x8*)(xb + base) = cvt8(x + base);
        }
        grid_barrier(flags + 511 * 128, tid, l, sub);
    }

    const float* Wx = d ? Wii_r : Wii_f;
    const float* Wh = d ? Whi_r : Whi_f;
    const float* bi = d ? bi_r  : bi_f;

    // ---- weight fragments: B-frag lane holds B[k=q*8+j][n=ln] = W[col n][k]
    bf16x8 wx[8][2], wh[8][2];
#pragma unroll
    for (int nt = 0; nt < 2; ++nt) {
        const int n = nt * 16 + ln;                    // local gate-col 0..31
        const int r = (n >> 3) * HH + u0 + (n & 7);    // W row: gate*H + unit
#pragma unroll
        for (int it = 0; it < 8; ++it) {
            const int off = r * 1024 + kw + it * 32 + q * 8;
            wx[it][nt] = cvt8(Wx + off);
            wh[it][nt] = cvt8(Wh + off);
        }
    }

    const int eb = tid >> 3;   // batch 0..31
    const int eu = tid & 7;    // local unit 0..7
    float bias[4];
#pragma unroll
    for (int gate = 0; gate < 4; ++gate)
        bias[gate] = bi[gate * HH + u0 + eu];

    float c_state = 0.0f;
    __shared__ float part[4][32][33];
    const f32x4 zero4 = {0.0f, 0.0f, 0.0f, 0.0f};

    for (int t = 0; t < SS; ++t) {
        const int tx = d ? (SS - 1 - t) : t;
        // read parity (t&1)^1 (parity 1 zeroed by memset => h0 = 0)
        const ushort* hrd = hb + (size_t)((((t & 1) ^ 1) * 2 + d) * 32) * 1024;

        f32x4 acc[2][2];
        acc[0][0] = zero4; acc[0][1] = zero4; acc[1][0] = zero4; acc[1][1] = zero4;

#pragma unroll
        for (int it = 0; it < 8; ++it) {
            const int ko = kw + it * 32 + q * 8;
            bf16x8 ax0, ax1;
            if (USE_XB) {
                ax0 = *(const bf16x8*)(xb + ((size_t)(ln * SS + tx)) * II + ko);
                ax1 = *(const bf16x8*)(xb + ((size_t)((16 + ln) * SS + tx)) * II + ko);
            } else {
                ax0 = cvt8(x + ((size_t)(ln * SS + tx)) * II + ko);
                ax1 = cvt8(x + ((size_t)((16 + ln) * SS + tx)) * II + ko);
            }
            bf16x8 ah0 = *(const bf16x8*)(hrd + ln * 1024 + ko);
            bf16x8 ah1 = *(const bf16x8*)(hrd + (16 + ln) * 1024 + ko);
            acc[0][0] = __builtin_amdgcn_mfma_f32_16x16x32_bf16(ax0, wx[it][0], acc[0][0], 0, 0, 0);
            acc[0][1] = __builtin_amdgcn_mfma_f32_16x16x32_bf16(ax0, wx[it][1], acc[0][1], 0, 0, 0);
            acc[1][0] = __builtin_amdgcn_mfma_f32_16x16x32_bf16(ax1, wx[it][0], acc[1][0], 0, 0, 0);
            acc[1][1] = __builtin_amdgcn_mfma_f32_16x16x32_bf16(ax1, wx[it][1], acc[1][1], 0, 0, 0);
            acc[0][0] = __builtin_amdgcn_mfma_f32_16x16x32_bf16(ah0, wh[it][0], acc[0][0], 0, 0, 0);
            acc[0][1] = __builtin_amdgcn_mfma_f32_16x16x32_bf16(ah0, wh[it][1], acc[0][1], 0, 0, 0);
            acc[1][0] = __builtin_amdgcn_mfma_f32_16x16x32_bf16(ah1, wh[it][0], acc[1][0], 0, 0, 0);
            acc[1][1] = __builtin_amdgcn_mfma_f32_16x16x32_bf16(ah1, wh[it][1], acc[1][1], 0, 0, 0);
        }

        // C/D: reg r of lane = D[m=q*4+r][n=ln]
#pragma unroll
        for (int mt = 0; mt < 2; ++mt)
#pragma unroll
            for (int nt = 0; nt < 2; ++nt)
#pragma unroll
                for (int r4 = 0; r4 < 4; ++r4)
                    part[w][mt * 16 + q * 4 + r4][nt * 16 + ln] = acc[mt][nt][r4];
        __syncthreads();

        float gi[4];
#pragma unroll
        for (int gate = 0; gate < 4; ++gate) {
            float s = bias[gate];
#pragma unroll
            for (int w2 = 0; w2 < 4; ++w2) s += part[w2][eb][gate * 8 + eu];
            gi[gate] = s;
        }
        const float igate = sigm(gi[0]);
        const float fgate = sigm(gi[1]);
        const float ggate = tanh_f(gi[2]);
        const float ogate = sigm(gi[3]);
        c_state = fgate * c_state + igate * ggate;
        const float hv = ogate * tanh_f(c_state);

        out[((size_t)(eb * SS + tx)) * (2 * HH) + d * HH + u0 + eu] = hv;
        // publish h (bf16) with cache-bypassing agent-scope store
        __hip_atomic_store(hb + (size_t)(((t & 1) * 2 + d) * 32 + eb) * 1024 + u0 + eu,
                           (unsigned short)f2bf_s(hv),
                           __ATOMIC_RELAXED, __HIP_MEMORY_SCOPE_AGENT);

        if (t < SS - 1)
            grid_barrier(flags + t * 128, tid, l, sub);
        else
            __syncthreads();   // keep LDS lifetime tidy on last step
    }
}

extern "C" void kernel_launch(void* const* d_in, const int* in_sizes, int n_in,
                              void* d_out, int out_size, void* d_ws, size_t ws_size,
                              hipStream_t stream)
{
    const float* x    = (const float*)d_in[0];
    const float* Wii  = (const float*)d_in[1];
    const float* Whi  = (const float*)d_in[2];
    const float* bi   = (const float*)d_in[3];
    const float* WiiR = (const float*)d_in[4];
    const float* WhiR = (const float*)d_in[5];
    const float* biR  = (const float*)d_in[6];
    float* out = (float*)d_out;

    // ws: [0,256K) barrier counters (512 slots x 128 uints);
    //     [256K,512K) h ping-pong (2 parity x 2 dir x 32 b x 1024 u, bf16);
    //     [512K, 512K+32M) optional bf16 x copy.
    unsigned int* flags = (unsigned int*)d_ws;
    ushort* hb = (ushort*)((char*)d_ws + 256 * 1024);
    ushort* xb = (ushort*)((char*)d_ws + 512 * 1024);
    const int use_xb = (ws_size >= 512 * 1024 + (size_t)NELEM * 2) ? 1 : 0;

    hipMemsetAsync(d_ws, 0, 512 * 1024, stream);   // zero counters + h0

    if (use_xb)
        hipLaunchKernelGGL((bilstm_persist<1>), dim3(256), dim3(256), 0, stream,
                           x, Wii, Whi, bi, WiiR, WhiR, biR, out, hb, flags, xb);
    else
        hipLaunchKernelGGL((bilstm_persist<0>), dim3(256), dim3(256), 0, stream,
                           x, Wii, Whi, bi, WiiR, WhiR, biR, out, hb, flags, xb);
}

// Round 3
// 11867.645 us; speedup vs baseline: 2.2752x; 2.2752x over previous
//
#include <hip/hip_runtime.h>

#define SS 512
#define II 1024
#define HH 1024
#define NELEM (32 * SS * II)   // B*S*I elements of x

typedef short bf16x8 __attribute__((ext_vector_type(8)));
typedef float f32x4 __attribute__((ext_vector_type(4)));

__device__ __forceinline__ short f2bf_s(float f) {
    union { float fv; unsigned int i; } v; v.fv = f;
    unsigned int r = v.i + 0x7FFF + ((v.i >> 16) & 1);  // RNE
    return (short)(r >> 16);
}
__device__ __forceinline__ float sigm(float x)   { return 1.0f / (1.0f + __expf(-x)); }
__device__ __forceinline__ float tanh_f(float x) { return 2.0f / (1.0f + __expf(-2.0f * x)) - 1.0f; }

__device__ __forceinline__ bf16x8 cvt8(const float* p) {
    bf16x8 r;
#pragma unroll
    for (int j = 0; j < 8; ++j) r[j] = f2bf_s(p[j]);
    return r;
}

// Pre-pass: x f32 -> bf16 (exactly covers NELEM with 8192 x 256 x 8)
__global__ void __launch_bounds__(256)
cvt_x_kernel(const float* __restrict__ x, ushort* __restrict__ xb) {
    const int i = (blockIdx.x * 256 + threadIdx.x) * 8;
    *(bf16x8*)(xb + i) = cvt8(x + i);
}

// Persistent BiLSTM, fence-free tagged h exchange.
// Grid 256x256. Block g: dir d=g>>7, owns 8 h-units (32 gate-cols). Weights
// bf16 register-resident (128 VGPR/lane). 4 waves K-split (256 k each) ->
// LDS reduce -> gates + c/h update. h published as tagged dwords
// (hi16 = bf16 value, lo16 = t+1) via relaxed agent atomics; readers
// poll-retry tags — no fences, no barrier, 2-slot ping-pong (max skew 1 step).
template <int USE_XB>
__global__ void __launch_bounds__(256, 1)
bilstm_persist(const float* __restrict__ x,
               const float* __restrict__ Wii_f, const float* __restrict__ Whi_f,
               const float* __restrict__ bi_f,
               const float* __restrict__ Wii_r, const float* __restrict__ Whi_r,
               const float* __restrict__ bi_r,
               float* __restrict__ out, unsigned int* __restrict__ hb,
               const ushort* __restrict__ xb)
{
    const int g   = blockIdx.x;
    const int d   = g >> 7;
    const int u0  = (g & 127) * 8;
    const int tid = threadIdx.x;
    const int w   = tid >> 6;
    const int l   = tid & 63;
    const int q   = l >> 4;
    const int ln  = l & 15;
    const int kw  = w * 256;

    const float* Wx = d ? Wii_r : Wii_f;
    const float* Wh = d ? Whi_r : Whi_f;
    const float* bi = d ? bi_r  : bi_f;

    // Weight fragments: B-frag lane holds B[k=q*8+j][n=ln] = W[col n][k]
    bf16x8 wx[8][2], wh[8][2];
#pragma unroll
    for (int nt = 0; nt < 2; ++nt) {
        const int n = nt * 16 + ln;                    // local gate-col 0..31
        const int r = (n >> 3) * HH + u0 + (n & 7);    // W row: gate*H + unit
#pragma unroll
        for (int it = 0; it < 8; ++it) {
            const int off = r * 1024 + kw + it * 32 + q * 8;
            wx[it][nt] = cvt8(Wx + off);
            wh[it][nt] = cvt8(Wh + off);
        }
    }

    const int eb = tid >> 3;   // batch 0..31
    const int eu = tid & 7;    // local unit 0..7
    float bias[4];
#pragma unroll
    for (int gate = 0; gate < 4; ++gate)
        bias[gate] = bi[gate * HH + u0 + eu];

    float c_state = 0.0f;
    __shared__ float part[4][32][33];
    const f32x4 zero4 = {0.0f, 0.0f, 0.0f, 0.0f};

    for (int t = 0; t < SS; ++t) {
        const int tx = d ? (SS - 1 - t) : t;
        const unsigned int want = (unsigned int)t;
        // step t reads h(t-1) from slot (t-1)&1 = (t&1)^1; writes slot t&1.
        const unsigned int* hrd = hb + (size_t)((((t & 1) ^ 1) * 2 + d) * 32) * 1024;
        unsigned int*       hwp = hb + (size_t)(((t & 1) * 2 + d) * 32) * 1024;

        f32x4 acc[2][2];
        acc[0][0] = zero4; acc[0][1] = zero4; acc[1][0] = zero4; acc[1][1] = zero4;

        // depth-2 pipelined tagged h loads: hbuf[s][0..7]=m-tile0, [8..15]=m-tile1
        unsigned int hbuf[3][16];
#pragma unroll
        for (int pf = 0; pf < 2; ++pf) {
            const unsigned int* p0 = hrd + ln * 1024 + kw + pf * 32 + q * 8;
#pragma unroll
            for (int j = 0; j < 8; ++j) {
                hbuf[pf][j]     = __hip_atomic_load(p0 + j,            __ATOMIC_RELAXED, __HIP_MEMORY_SCOPE_AGENT);
                hbuf[pf][8 + j] = __hip_atomic_load(p0 + 16 * 1024 + j, __ATOMIC_RELAXED, __HIP_MEMORY_SCOPE_AGENT);
            }
        }

#pragma unroll
        for (int it = 0; it < 8; ++it) {
            const int ko = kw + it * 32 + q * 8;
            // prefetch chunk it+2
            if (it < 6) {
                const unsigned int* p0 = hrd + ln * 1024 + ko + 64;
#pragma unroll
                for (int j = 0; j < 8; ++j) {
                    hbuf[(it + 2) % 3][j]     = __hip_atomic_load(p0 + j,             __ATOMIC_RELAXED, __HIP_MEMORY_SCOPE_AGENT);
                    hbuf[(it + 2) % 3][8 + j] = __hip_atomic_load(p0 + 16 * 1024 + j, __ATOMIC_RELAXED, __HIP_MEMORY_SCOPE_AGENT);
                }
            }

            // x part first (independent of h) — covers h load latency
            bf16x8 ax0, ax1;
            if (USE_XB) {
                ax0 = *(const bf16x8*)(xb + ((size_t)(ln * SS + tx)) * II + ko);
                ax1 = *(const bf16x8*)(xb + ((size_t)((16 + ln) * SS + tx)) * II + ko);
            } else {
                ax0 = cvt8(x + ((size_t)(ln * SS + tx)) * II + ko);
                ax1 = cvt8(x + ((size_t)((16 + ln) * SS + tx)) * II + ko);
            }
            acc[0][0] = __builtin_amdgcn_mfma_f32_16x16x32_bf16(ax0, wx[it][0], acc[0][0], 0, 0, 0);
            acc[0][1] = __builtin_amdgcn_mfma_f32_16x16x32_bf16(ax0, wx[it][1], acc[0][1], 0, 0, 0);
            acc[1][0] = __builtin_amdgcn_mfma_f32_16x16x32_bf16(ax1, wx[it][0], acc[1][0], 0, 0, 0);
            acc[1][1] = __builtin_amdgcn_mfma_f32_16x16x32_bf16(ax1, wx[it][1], acc[1][1], 0, 0, 0);

            // check tags & retry stragglers
            unsigned int* cb = hbuf[it % 3];
            const unsigned int* p0 = hrd + ln * 1024 + ko;
#pragma unroll
            for (int j = 0; j < 8; ++j) {
                while ((cb[j] & 0xFFFFu) != want)
                    cb[j] = __hip_atomic_load(p0 + j, __ATOMIC_RELAXED, __HIP_MEMORY_SCOPE_AGENT);
                while ((cb[8 + j] & 0xFFFFu) != want)
                    cb[8 + j] = __hip_atomic_load(p0 + 16 * 1024 + j, __ATOMIC_RELAXED, __HIP_MEMORY_SCOPE_AGENT);
            }
            bf16x8 ah0, ah1;
#pragma unroll
            for (int j = 0; j < 8; ++j) {
                ah0[j] = (short)(cb[j] >> 16);
                ah1[j] = (short)(cb[8 + j] >> 16);
            }
            acc[0][0] = __builtin_amdgcn_mfma_f32_16x16x32_bf16(ah0, wh[it][0], acc[0][0], 0, 0, 0);
            acc[0][1] = __builtin_amdgcn_mfma_f32_16x16x32_bf16(ah0, wh[it][1], acc[0][1], 0, 0, 0);
            acc[1][0] = __builtin_amdgcn_mfma_f32_16x16x32_bf16(ah1, wh[it][0], acc[1][0], 0, 0, 0);
            acc[1][1] = __builtin_amdgcn_mfma_f32_16x16x32_bf16(ah1, wh[it][1], acc[1][1], 0, 0, 0);
        }

        // C/D: reg r of lane = D[m=q*4+r][n=ln]
#pragma unroll
        for (int mt = 0; mt < 2; ++mt)
#pragma unroll
            for (int nt = 0; nt < 2; ++nt)
#pragma unroll
                for (int r4 = 0; r4 < 4; ++r4)
                    part[w][mt * 16 + q * 4 + r4][nt * 16 + ln] = acc[mt][nt][r4];
        __syncthreads();

        float gi[4];
#pragma unroll
        for (int gate = 0; gate < 4; ++gate) {
            float s = bias[gate];
#pragma unroll
            for (int w2 = 0; w2 < 4; ++w2) s += part[w2][eb][gate * 8 + eu];
            gi[gate] = s;
        }
        const float igate = sigm(gi[0]);
        const float fgate = sigm(gi[1]);
        const float ggate = tanh_f(gi[2]);
        const float ogate = sigm(gi[3]);
        c_state = fgate * c_state + igate * ggate;
        const float hv = ogate * tanh_f(c_state);

        out[((size_t)(eb * SS + tx)) * (2 * HH) + d * HH + u0 + eu] = hv;

        // publish tagged h: hi16 = bf16(h), lo16 = t+1
        const unsigned int word =
            ((unsigned int)(unsigned short)f2bf_s(hv) << 16) | (unsigned int)(t + 1);
        __hip_atomic_store(hwp + (size_t)eb * 1024 + u0 + eu, word,
                           __ATOMIC_RELAXED, __HIP_MEMORY_SCOPE_AGENT);

        __syncthreads();   // protect LDS 'part' reuse next step
    }
}

extern "C" void kernel_launch(void* const* d_in, const int* in_sizes, int n_in,
                              void* d_out, int out_size, void* d_ws, size_t ws_size,
                              hipStream_t stream)
{
    const float* x    = (const float*)d_in[0];
    const float* Wii  = (const float*)d_in[1];
    const float* Whi  = (const float*)d_in[2];
    const float* bi   = (const float*)d_in[3];
    const float* WiiR = (const float*)d_in[4];
    const float* WhiR = (const float*)d_in[5];
    const float* biR  = (const float*)d_in[6];
    float* out = (float*)d_out;

    // ws: [0,512K) tagged h ping-pong (2 slots x 2 dir x 32 b x 1024 u dwords)
    //     [512K, 512K+32M) bf16 x copy
    unsigned int* hb = (unsigned int*)d_ws;
    ushort* xb = (ushort*)((char*)d_ws + 512 * 1024);
    const int use_xb = (ws_size >= 512 * 1024 + (size_t)NELEM * 2) ? 1 : 0;

    hipMemsetAsync(d_ws, 0, 512 * 1024, stream);   // zero tags => h0 = 0, tag 0

    if (use_xb) {
        hipLaunchKernelGGL(cvt_x_kernel, dim3(NELEM / (256 * 8)), dim3(256), 0, stream, x, xb);
        hipLaunchKernelGGL((bilstm_persist<1>), dim3(256), dim3(256), 0, stream,
                           x, Wii, Whi, bi, WiiR, WhiR, biR, out, hb, xb);
    } else {
        hipLaunchKernelGGL((bilstm_persist<0>), dim3(256), dim3(256), 0, stream,
                           x, Wii, Whi, bi, WiiR, WhiR, biR, out, hb, xb);
    }
}

// Round 4
// 10163.969 us; speedup vs baseline: 2.6565x; 1.1676x over previous
//
#include <hip/hip_runtime.h>

#define SS 512
#define II 1024
#define HH 1024
#define NELEM (32 * SS * II)   // B*S*I elements of x

typedef short bf16x8 __attribute__((ext_vector_type(8)));
typedef float f32x4 __attribute__((ext_vector_type(4)));
typedef unsigned int u32;
typedef u32 u32x4 __attribute__((ext_vector_type(4)));

__device__ __forceinline__ short f2bf_s(float f) {
    union { float fv; u32 i; } v; v.fv = f;
    u32 r = v.i + 0x7FFF + ((v.i >> 16) & 1);  // RNE
    return (short)(r >> 16);
}
__device__ __forceinline__ float sigm(float x)   { return 1.0f / (1.0f + __expf(-x)); }
__device__ __forceinline__ float tanh_f(float x) { return 2.0f / (1.0f + __expf(-2.0f * x)) - 1.0f; }

__device__ __forceinline__ bf16x8 cvt8(const float* p) {
    bf16x8 r;
#pragma unroll
    for (int j = 0; j < 8; ++j) r[j] = f2bf_s(p[j]);
    return r;
}

// Pre-pass: x f32 -> bf16 (exactly covers NELEM with 8192 x 256 x 8)
__global__ void __launch_bounds__(256)
cvt_x_kernel(const float* __restrict__ x, ushort* __restrict__ xb) {
    const int i = (blockIdx.x * 256 + threadIdx.x) * 8;
    *(bf16x8*)(xb + i) = cvt8(x + i);
}

#define A_LD(p) __hip_atomic_load((p), __ATOMIC_RELAXED, __HIP_MEMORY_SCOPE_AGENT)
#define A_ST(p, v) __hip_atomic_store((p), (v), __ATOMIC_RELAXED, __HIP_MEMORY_SCOPE_AGENT)

// Persistent BiLSTM, flag-gated speculative h exchange.
// Grid 256x256. Block g: dir d=g>>7, owns 8 h-units (32 gate-cols). Weights
// bf16 register-resident. h stored PACKED (2 bf16 units / dword; dword j =
// units {2j,2j+1} => 4 consecutive dwords == one bf16x8 A-fragment, bit-cast,
// no unpack). Sync: one write-once flag per (producer block, step), relaxed
// agent atomics only (no fences / no L2 writeback-invalidate). Consumers
// speculatively bulk-load h + the 8 producer flags they depend on, overlap
// with x-MFMAs, and re-load only stale chunks (rare). 2-slot ping-pong,
// max skew 1 step: stale slot data => stale flag => reload.
template <int USE_XB>
__global__ void __launch_bounds__(256, 1)
bilstm_persist(const float* __restrict__ x,
               const float* __restrict__ Wii_f, const float* __restrict__ Whi_f,
               const float* __restrict__ bi_f,
               const float* __restrict__ Wii_r, const float* __restrict__ Whi_r,
               const float* __restrict__ bi_r,
               float* __restrict__ out, u32* __restrict__ hb,
               u32* __restrict__ flags, const ushort* __restrict__ xb)
{
    const int g   = blockIdx.x;
    const int d   = g >> 7;
    const int u0  = (g & 127) * 8;
    const int tid = threadIdx.x;
    const int w   = tid >> 6;
    const int l   = tid & 63;
    const int q   = l >> 4;
    const int ln  = l & 15;
    const int kw  = w * 256;
    const int pbase = d * 128 + (kw >> 3);   // first of this wave's 32 producers

    const float* Wx = d ? Wii_r : Wii_f;
    const float* Wh = d ? Whi_r : Whi_f;
    const float* bi = d ? bi_r  : bi_f;

    // Weight fragments: B-frag lane holds B[k=q*8+j][n=ln] = W[col n][k]
    bf16x8 wx[8][2], wh[8][2];
#pragma unroll
    for (int nt = 0; nt < 2; ++nt) {
        const int n = nt * 16 + ln;                    // local gate-col 0..31
        const int r = (n >> 3) * HH + u0 + (n & 7);    // W row: gate*H + unit
#pragma unroll
        for (int it = 0; it < 8; ++it) {
            const int off = r * 1024 + kw + it * 32 + q * 8;
            wx[it][nt] = cvt8(Wx + off);
            wh[it][nt] = cvt8(Wh + off);
        }
    }

    const int eb = tid >> 3;   // batch 0..31
    const int eu = tid & 7;    // local unit 0..7
    float bias[4];
#pragma unroll
    for (int gate = 0; gate < 4; ++gate)
        bias[gate] = bi[gate * HH + u0 + eu];

    float c_state = 0.0f;
    __shared__ float part[4][32][33];
    const f32x4 zero4 = {0.0f, 0.0f, 0.0f, 0.0f};

    for (int t = 0; t < SS; ++t) {
        const int tx = d ? (SS - 1 - t) : t;
        // packed slabs: slot*2+d, 32 rows x 512 dwords
        const u32* hrd = hb + (size_t)(((t & 1) ^ 1) * 2 + d) * 32 * 512;
        u32*       hwp = hb + (size_t)((t & 1) * 2 + d) * 32 * 512;

        f32x4 acc[2][2];
        acc[0][0] = zero4; acc[0][1] = zero4; acc[1][0] = zero4; acc[1][1] = zero4;

        u32 fl[8];
        u32x4 hr0[8], hr1[8];   // chunk fragments, rows ln / ln+16

        const u32* fb  = flags + (size_t)(t - 1) * 256 + pbase + q; // +it*4
        const u32* hp0 = hrd + ln * 512 + (kw >> 1) + q * 4;        // +it*16

        if (t > 0) {
            // speculative batch: 8 flags + 64 h dwords, all in flight at once
#pragma unroll
            for (int it = 0; it < 8; ++it) fl[it] = A_LD(fb + it * 4);
#pragma unroll
            for (int it = 0; it < 8; ++it) {
#pragma unroll
                for (int j = 0; j < 4; ++j) {
                    hr0[it][j] = A_LD(hp0 + it * 16 + j);
                    hr1[it][j] = A_LD(hp0 + 16 * 512 + it * 16 + j);
                }
            }
        }

        // ---- x part (independent of h) overlaps the h/flag loads ----
#pragma unroll
        for (int it = 0; it < 8; ++it) {
            const int ko = kw + it * 32 + q * 8;
            bf16x8 ax0, ax1;
            if (USE_XB) {
                ax0 = *(const bf16x8*)(xb + ((size_t)(ln * SS + tx)) * II + ko);
                ax1 = *(const bf16x8*)(xb + ((size_t)((16 + ln) * SS + tx)) * II + ko);
            } else {
                ax0 = cvt8(x + ((size_t)(ln * SS + tx)) * II + ko);
                ax1 = cvt8(x + ((size_t)((16 + ln) * SS + tx)) * II + ko);
            }
            acc[0][0] = __builtin_amdgcn_mfma_f32_16x16x32_bf16(ax0, wx[it][0], acc[0][0], 0, 0, 0);
            acc[0][1] = __builtin_amdgcn_mfma_f32_16x16x32_bf16(ax0, wx[it][1], acc[0][1], 0, 0, 0);
            acc[1][0] = __builtin_amdgcn_mfma_f32_16x16x32_bf16(ax1, wx[it][0], acc[1][0], 0, 0, 0);
            acc[1][1] = __builtin_amdgcn_mfma_f32_16x16x32_bf16(ax1, wx[it][1], acc[1][1], 0, 0, 0);
        }

        // ---- h part: confirm flags, reload stale chunks (rare), MFMA ----
        if (t > 0) {
#pragma unroll
            for (int it = 0; it < 8; ++it) {
                if (fl[it] == 0u) {
                    while (A_LD(fb + it * 4) == 0u) __builtin_amdgcn_s_sleep(1);
#pragma unroll
                    for (int j = 0; j < 4; ++j) {
                        hr0[it][j] = A_LD(hp0 + it * 16 + j);
                        hr1[it][j] = A_LD(hp0 + 16 * 512 + it * 16 + j);
                    }
                }
                const bf16x8 ah0 = __builtin_bit_cast(bf16x8, hr0[it]);
                const bf16x8 ah1 = __builtin_bit_cast(bf16x8, hr1[it]);
                acc[0][0] = __builtin_amdgcn_mfma_f32_16x16x32_bf16(ah0, wh[it][0], acc[0][0], 0, 0, 0);
                acc[0][1] = __builtin_amdgcn_mfma_f32_16x16x32_bf16(ah0, wh[it][1], acc[0][1], 0, 0, 0);
                acc[1][0] = __builtin_amdgcn_mfma_f32_16x16x32_bf16(ah1, wh[it][0], acc[1][0], 0, 0, 0);
                acc[1][1] = __builtin_amdgcn_mfma_f32_16x16x32_bf16(ah1, wh[it][1], acc[1][1], 0, 0, 0);
            }
        }

        // C/D: reg r of lane = D[m=q*4+r][n=ln]
#pragma unroll
        for (int mt = 0; mt < 2; ++mt)
#pragma unroll
            for (int nt = 0; nt < 2; ++nt)
#pragma unroll
                for (int r4 = 0; r4 < 4; ++r4)
                    part[w][mt * 16 + q * 4 + r4][nt * 16 + ln] = acc[mt][nt][r4];
        __syncthreads();

        float gi[4];
#pragma unroll
        for (int gate = 0; gate < 4; ++gate) {
            float s = bias[gate];
#pragma unroll
            for (int w2 = 0; w2 < 4; ++w2) s += part[w2][eb][gate * 8 + eu];
            gi[gate] = s;
        }
        const float igate = sigm(gi[0]);
        const float fgate = sigm(gi[1]);
        const float ggate = tanh_f(gi[2]);
        const float ogate = sigm(gi[3]);
        c_state = fgate * c_state + igate * ggate;
        const float hv = ogate * tanh_f(c_state);

        out[((size_t)(eb * SS + tx)) * (2 * HH) + d * HH + u0 + eu] = hv;

        // pack pair (even unit low, odd unit high) and publish
        const u32 mine = (u32)(unsigned short)f2bf_s(hv);
        const u32 partner = (u32)__shfl_xor((int)mine, 1, 64);
        if ((tid & 1) == 0)
            A_ST(hwp + eb * 512 + ((u0 + eu) >> 1), mine | (partner << 16));

        __builtin_amdgcn_s_waitcnt(0);   // h stores ack'd at coherence point
        __syncthreads();                 // all 4 waves drained (also LDS reuse)
        if (tid == 0)
            A_ST(flags + (size_t)t * 256 + g, 1u);
    }
}

extern "C" void kernel_launch(void* const* d_in, const int* in_sizes, int n_in,
                              void* d_out, int out_size, void* d_ws, size_t ws_size,
                              hipStream_t stream)
{
    const float* x    = (const float*)d_in[0];
    const float* Wii  = (const float*)d_in[1];
    const float* Whi  = (const float*)d_in[2];
    const float* bi   = (const float*)d_in[3];
    const float* WiiR = (const float*)d_in[4];
    const float* WhiR = (const float*)d_in[5];
    const float* biR  = (const float*)d_in[6];
    float* out = (float*)d_out;

    // ws: [0,256K) packed h ping-pong (2 slots x 2 dir x 32 b x 512 dwords)
    //     [256K,768K) flags (512 steps x 256 blocks, write-once)
    //     [1M, 1M+32M) bf16 x copy
    u32* hb    = (u32*)d_ws;
    u32* flags = (u32*)((char*)d_ws + 256 * 1024);
    ushort* xb = (ushort*)((char*)d_ws + 1024 * 1024);
    const int use_xb = (ws_size >= 1024 * 1024 + (size_t)NELEM * 2) ? 1 : 0;

    hipMemsetAsync(d_ws, 0, 768 * 1024, stream);   // zero h slabs + flags

    if (use_xb) {
        hipLaunchKernelGGL(cvt_x_kernel, dim3(NELEM / (256 * 8)), dim3(256), 0, stream, x, xb);
        hipLaunchKernelGGL((bilstm_persist<1>), dim3(256), dim3(256), 0, stream,
                           x, Wii, Whi, bi, WiiR, WhiR, biR, out, hb, flags, xb);
    } else {
        hipLaunchKernelGGL((bilstm_persist<0>), dim3(256), dim3(256), 0, stream,
                           x, Wii, Whi, bi, WiiR, WhiR, biR, out, hb, flags, xb);
    }
}